// Round 1
// baseline (359.227 us; speedup 1.0000x reference)
//
#include <hip/hip_runtime.h>

// SparseLayer: 100000 independent tiny MLPs, 5 -> 2 -> 2 -> 1, batch 128, fp32.
// Memory-bound: ~314 MB total traffic -> ~50 us floor at 6.3 TB/s.
//
// Mapping: 32 lanes per net, each lane owns 4 batch columns (float4).
// 256-thread block = 8 nets. Grid = 100000/8 = 12500 blocks exactly.

#define NNETS   100000
#define IFACE   5
#define BATCH   128
#define B4      (BATCH / 4)        // 32 float4 per row
#define NETS_PER_BLOCK 8

__device__ __forceinline__ float4 f4mul(float s, float4 v) {
    float4 r;
    r.x = s * v.x; r.y = s * v.y; r.z = s * v.z; r.w = s * v.w;
    return r;
}
__device__ __forceinline__ float4 f4fma(float s, float4 v, float4 acc) {
    acc.x = fmaf(s, v.x, acc.x);
    acc.y = fmaf(s, v.y, acc.y);
    acc.z = fmaf(s, v.z, acc.z);
    acc.w = fmaf(s, v.w, acc.w);
    return acc;
}

__global__ __launch_bounds__(256) void sparse_mlp_kernel(
    const float* __restrict__ x,   // [NNETS*IFACE, BATCH]
    const float* __restrict__ w0,  // [NNETS, 2, 5]
    const float* __restrict__ w1,  // [NNETS, 2, 2]
    const float* __restrict__ w2,  // [NNETS, 1, 2]
    float* __restrict__ out)       // [NNETS, BATCH]
{
    const int t    = threadIdx.x;
    const int lane = t & 31;                        // float4 column within the net's rows
    const int net  = blockIdx.x * NETS_PER_BLOCK + (t >> 5);

    // ---- load x rows (coalesced: 32 consecutive float4 per row) ----
    const float4* x4 = (const float4*)x;
    const long xbase = (long)net * IFACE * B4 + lane;
    float4 in0 = x4[xbase + 0 * B4];
    float4 in1 = x4[xbase + 1 * B4];
    float4 in2 = x4[xbase + 2 * B4];
    float4 in3 = x4[xbase + 3 * B4];
    float4 in4 = x4[xbase + 4 * B4];

    // ---- load weights (small; broadcast within 32-lane group, L1/L2 absorbs) ----
    // w0: 10 floats/net, base n*40 B -> 8B aligned -> float2 loads
    const float2* w0p = (const float2*)w0;
    const long w0b = (long)net * 5;
    float2 p0 = w0p[w0b + 0];   // w0[0][0], w0[0][1]
    float2 p1 = w0p[w0b + 1];   // w0[0][2], w0[0][3]
    float2 p2 = w0p[w0b + 2];   // w0[0][4], w0[1][0]
    float2 p3 = w0p[w0b + 3];   // w0[1][1], w0[1][2]
    float2 p4 = w0p[w0b + 4];   // w0[1][3], w0[1][4]
    // w1: 4 floats/net, 16B aligned -> float4
    float4 a = ((const float4*)w1)[net];            // a00,a01,a10,a11
    // w2: 2 floats/net, 8B aligned -> float2
    float2 c = ((const float2*)w2)[net];            // c0,c1

    // ---- layer 0: h0[j] = sum_i w0[j][i] * in[i] ----
    float4 h00 = f4mul(p0.x, in0);
    h00 = f4fma(p0.y, in1, h00);
    h00 = f4fma(p1.x, in2, h00);
    h00 = f4fma(p1.y, in3, h00);
    h00 = f4fma(p2.x, in4, h00);

    float4 h01 = f4mul(p2.y, in0);
    h01 = f4fma(p3.x, in1, h01);
    h01 = f4fma(p3.y, in2, h01);
    h01 = f4fma(p4.x, in3, h01);
    h01 = f4fma(p4.y, in4, h01);

    // ---- layer 1: h1[j] = w1[j][0]*h00 + w1[j][1]*h01 ----
    float4 h10 = f4mul(a.x, h00);
    h10 = f4fma(a.y, h01, h10);
    float4 h11 = f4mul(a.z, h00);
    h11 = f4fma(a.w, h01, h11);

    // ---- layer 2: o = c0*h10 + c1*h11 ----
    float4 o = f4mul(c.x, h10);
    o = f4fma(c.y, h11, o);

    // ---- store (coalesced float4) ----
    ((float4*)out)[(long)net * B4 + lane] = o;
}

extern "C" void kernel_launch(void* const* d_in, const int* in_sizes, int n_in,
                              void* d_out, int out_size, void* d_ws, size_t ws_size,
                              hipStream_t stream) {
    const float* x  = (const float*)d_in[0];
    const float* w0 = (const float*)d_in[1];
    const float* w1 = (const float*)d_in[2];
    const float* w2 = (const float*)d_in[3];
    float* out = (float*)d_out;

    dim3 block(256);
    dim3 grid(NNETS / NETS_PER_BLOCK);   // 12500, exact
    sparse_mlp_kernel<<<grid, block, 0, stream>>>(x, w0, w1, w2, out);
}

// Round 3
// 343.057 us; speedup vs baseline: 1.0471x; 1.0471x over previous
//
#include <hip/hip_runtime.h>

// SparseLayer: 100000 independent tiny MLPs, 5 -> 2 -> 2 -> 1, batch 128, fp32.
// HBM-bound: x 256 MB read + out 51 MB write + weights 6.4 MB -> ~50 us floor
// at 6.3 TB/s achievable. FLOPs trivial (0.41 GFLOP).
//
// Mapping: 32 lanes per net, each lane owns 4 batch columns (float4).
// 256-thread block = 8 nets. Grid = 100000/8 = 12500 blocks exactly.
//
// R3: nontemporal x loads / out stores via native ext_vector_type(4) float
// (HIP's float4 is a class -> rejected by __builtin_nontemporal_*).

#define NNETS   100000
#define IFACE   5
#define BATCH   128
#define B4      (BATCH / 4)        // 32 float4 per row
#define NETS_PER_BLOCK 8

typedef float vfloat4 __attribute__((ext_vector_type(4)));
typedef float vfloat2 __attribute__((ext_vector_type(2)));

__device__ __forceinline__ vfloat4 f4fma(float s, vfloat4 v, vfloat4 acc) {
    acc.x = fmaf(s, v.x, acc.x);
    acc.y = fmaf(s, v.y, acc.y);
    acc.z = fmaf(s, v.z, acc.z);
    acc.w = fmaf(s, v.w, acc.w);
    return acc;
}

__global__ __launch_bounds__(256) void sparse_mlp_kernel(
    const float* __restrict__ x,   // [NNETS*IFACE, BATCH]
    const float* __restrict__ w0,  // [NNETS, 2, 5]
    const float* __restrict__ w1,  // [NNETS, 2, 2]
    const float* __restrict__ w2,  // [NNETS, 1, 2]
    float* __restrict__ out)       // [NNETS, BATCH]
{
    const int t    = threadIdx.x;
    const int lane = t & 31;                        // float4 column within the net's rows
    const int net  = blockIdx.x * NETS_PER_BLOCK + (t >> 5);

    // ---- load x rows (coalesced, streaming/nontemporal) ----
    const vfloat4* xr = (const vfloat4*)x + (long)net * IFACE * B4 + lane;
    vfloat4 in0 = __builtin_nontemporal_load(xr + 0 * B4);
    vfloat4 in1 = __builtin_nontemporal_load(xr + 1 * B4);
    vfloat4 in2 = __builtin_nontemporal_load(xr + 2 * B4);
    vfloat4 in3 = __builtin_nontemporal_load(xr + 3 * B4);
    vfloat4 in4 = __builtin_nontemporal_load(xr + 4 * B4);

    // ---- load weights (small; broadcast within 32-lane group; keep cached) ----
    // w0: 10 floats/net, base n*40 B -> 8B aligned -> float2 loads
    const vfloat2* w0p = (const vfloat2*)w0;
    const long w0b = (long)net * 5;
    vfloat2 p0 = w0p[w0b + 0];   // w0[0][0], w0[0][1]
    vfloat2 p1 = w0p[w0b + 1];   // w0[0][2], w0[0][3]
    vfloat2 p2 = w0p[w0b + 2];   // w0[0][4], w0[1][0]
    vfloat2 p3 = w0p[w0b + 3];   // w0[1][1], w0[1][2]
    vfloat2 p4 = w0p[w0b + 4];   // w0[1][3], w0[1][4]
    // w1: 4 floats/net, 16B aligned -> float4
    vfloat4 a = ((const vfloat4*)w1)[net];          // a00,a01,a10,a11
    // w2: 2 floats/net, 8B aligned -> float2
    vfloat2 c = ((const vfloat2*)w2)[net];          // c0,c1

    // ---- layer 0: h0[j] = sum_i w0[j][i] * in[i] ----
    vfloat4 h00 = p0.x * in0;
    h00 = f4fma(p0.y, in1, h00);
    h00 = f4fma(p1.x, in2, h00);
    h00 = f4fma(p1.y, in3, h00);
    h00 = f4fma(p2.x, in4, h00);

    vfloat4 h01 = p2.y * in0;
    h01 = f4fma(p3.x, in1, h01);
    h01 = f4fma(p3.y, in2, h01);
    h01 = f4fma(p4.x, in3, h01);
    h01 = f4fma(p4.y, in4, h01);

    // ---- layer 1 ----
    vfloat4 h10 = a.x * h00;
    h10 = f4fma(a.y, h01, h10);
    vfloat4 h11 = a.z * h00;
    h11 = f4fma(a.w, h01, h11);

    // ---- layer 2 ----
    vfloat4 o = c.x * h10;
    o = f4fma(c.y, h11, o);

    // ---- store (coalesced float4, nontemporal) ----
    __builtin_nontemporal_store(o, (vfloat4*)out + (long)net * B4 + lane);
}

extern "C" void kernel_launch(void* const* d_in, const int* in_sizes, int n_in,
                              void* d_out, int out_size, void* d_ws, size_t ws_size,
                              hipStream_t stream) {
    const float* x  = (const float*)d_in[0];
    const float* w0 = (const float*)d_in[1];
    const float* w1 = (const float*)d_in[2];
    const float* w2 = (const float*)d_in[3];
    float* out = (float*)d_out;

    dim3 block(256);
    dim3 grid(NNETS / NETS_PER_BLOCK);   // 12500, exact
    sparse_mlp_kernel<<<grid, block, 0, stream>>>(x, w0, w1, w2, out);
}

// Round 4
// 339.171 us; speedup vs baseline: 1.0591x; 1.0115x over previous
//
#include <hip/hip_runtime.h>

// SparseLayer: 100000 independent tiny MLPs, 5 -> 2 -> 2 -> 1, batch 128, fp32.
// HBM-bound: x 256 MB read + out 51 MB write + weights 6.4 MB -> ~48 us floor
// at 6.6 TB/s achieved-by-fills. FLOPs trivial (0.41 GFLOP).
//
// R4: 2 adjacent nets per thread (32 lanes x 4 cols each) -> 10 outstanding
// x-loads per thread for latency hiding; nt on ALL global accesses (x, out,
// and weights -- weights are broadcast-read by exactly one half-wave, no
// cross-wave reuse, so they're use-once at cache level too).
// Block 256 = 8 thread-groups x 2 nets = 16 nets; grid 100000/16 = 6250.

#define NNETS   100000
#define IFACE   5
#define BATCH   128
#define B4      (BATCH / 4)        // 32 float4 per row
#define NETS_PER_BLOCK 16

typedef float vfloat4 __attribute__((ext_vector_type(4)));
typedef float vfloat2 __attribute__((ext_vector_type(2)));

__device__ __forceinline__ vfloat4 f4fma(float s, vfloat4 v, vfloat4 acc) {
    acc.x = fmaf(s, v.x, acc.x);
    acc.y = fmaf(s, v.y, acc.y);
    acc.z = fmaf(s, v.z, acc.z);
    acc.w = fmaf(s, v.w, acc.w);
    return acc;
}

// Compute one net's 2-2-1 MLP for 4 batch columns held in in0..in4.
__device__ __forceinline__ vfloat4 mlp_net(
    vfloat4 in0, vfloat4 in1, vfloat4 in2, vfloat4 in3, vfloat4 in4,
    vfloat2 p0, vfloat2 p1, vfloat2 p2, vfloat2 p3, vfloat2 p4,
    vfloat4 a, vfloat2 c)
{
    vfloat4 h00 = p0.x * in0;
    h00 = f4fma(p0.y, in1, h00);
    h00 = f4fma(p1.x, in2, h00);
    h00 = f4fma(p1.y, in3, h00);
    h00 = f4fma(p2.x, in4, h00);

    vfloat4 h01 = p2.y * in0;
    h01 = f4fma(p3.x, in1, h01);
    h01 = f4fma(p3.y, in2, h01);
    h01 = f4fma(p4.x, in3, h01);
    h01 = f4fma(p4.y, in4, h01);

    vfloat4 h10 = a.x * h00;
    h10 = f4fma(a.y, h01, h10);
    vfloat4 h11 = a.z * h00;
    h11 = f4fma(a.w, h01, h11);

    vfloat4 o = c.x * h10;
    o = f4fma(c.y, h11, o);
    return o;
}

__global__ __launch_bounds__(256) void sparse_mlp_kernel(
    const float* __restrict__ x,   // [NNETS*IFACE, BATCH]
    const float* __restrict__ w0,  // [NNETS, 2, 5]
    const float* __restrict__ w1,  // [NNETS, 2, 2]
    const float* __restrict__ w2,  // [NNETS, 1, 2]
    float* __restrict__ out)       // [NNETS, BATCH]
{
    const int t    = threadIdx.x;
    const int lane = t & 31;                      // float4 column within rows
    const int net0 = blockIdx.x * NETS_PER_BLOCK + (t >> 5) * 2;  // even net
    const int net1 = net0 + 1;

    // ---- issue ALL x loads up front (10 outstanding nt loads/thread) ----
    const vfloat4* xr0 = (const vfloat4*)x + (long)net0 * IFACE * B4 + lane;
    const vfloat4* xr1 = (const vfloat4*)x + (long)net1 * IFACE * B4 + lane;
    vfloat4 a0 = __builtin_nontemporal_load(xr0 + 0 * B4);
    vfloat4 a1 = __builtin_nontemporal_load(xr0 + 1 * B4);
    vfloat4 a2 = __builtin_nontemporal_load(xr0 + 2 * B4);
    vfloat4 a3 = __builtin_nontemporal_load(xr0 + 3 * B4);
    vfloat4 a4 = __builtin_nontemporal_load(xr0 + 4 * B4);
    vfloat4 b0 = __builtin_nontemporal_load(xr1 + 0 * B4);
    vfloat4 b1 = __builtin_nontemporal_load(xr1 + 1 * B4);
    vfloat4 b2 = __builtin_nontemporal_load(xr1 + 2 * B4);
    vfloat4 b3 = __builtin_nontemporal_load(xr1 + 3 * B4);
    vfloat4 b4 = __builtin_nontemporal_load(xr1 + 4 * B4);

    // ---- weight loads (broadcast within half-wave; use-once -> nt) ----
    // w0: 10 floats/net, 8B-aligned base -> float2; two nets = 10 float2s
    const vfloat2* w0p = (const vfloat2*)w0 + (long)net0 * 5;
    vfloat2 p0 = __builtin_nontemporal_load(w0p + 0);
    vfloat2 p1 = __builtin_nontemporal_load(w0p + 1);
    vfloat2 p2 = __builtin_nontemporal_load(w0p + 2);
    vfloat2 p3 = __builtin_nontemporal_load(w0p + 3);
    vfloat2 p4 = __builtin_nontemporal_load(w0p + 4);
    vfloat2 q0 = __builtin_nontemporal_load(w0p + 5);
    vfloat2 q1 = __builtin_nontemporal_load(w0p + 6);
    vfloat2 q2 = __builtin_nontemporal_load(w0p + 7);
    vfloat2 q3 = __builtin_nontemporal_load(w0p + 8);
    vfloat2 q4 = __builtin_nontemporal_load(w0p + 9);
    // w1: 4 floats/net, 16B aligned -> float4 each
    const vfloat4* w1p = (const vfloat4*)w1;
    vfloat4 wa = __builtin_nontemporal_load(w1p + net0);
    vfloat4 wb = __builtin_nontemporal_load(w1p + net1);
    // w2: 2 floats/net, 8B aligned -> float2 each
    const vfloat2* w2p = (const vfloat2*)w2;
    vfloat2 ca = __builtin_nontemporal_load(w2p + net0);
    vfloat2 cb = __builtin_nontemporal_load(w2p + net1);

    // ---- compute both nets ----
    vfloat4 o0 = mlp_net(a0, a1, a2, a3, a4, p0, p1, p2, p3, p4, wa, ca);
    vfloat4 o1 = mlp_net(b0, b1, b2, b3, b4, q0, q1, q2, q3, q4, wb, cb);

    // ---- stores (coalesced float4, nontemporal) ----
    __builtin_nontemporal_store(o0, (vfloat4*)out + (long)net0 * B4 + lane);
    __builtin_nontemporal_store(o1, (vfloat4*)out + (long)net1 * B4 + lane);
}

extern "C" void kernel_launch(void* const* d_in, const int* in_sizes, int n_in,
                              void* d_out, int out_size, void* d_ws, size_t ws_size,
                              hipStream_t stream) {
    const float* x  = (const float*)d_in[0];
    const float* w0 = (const float*)d_in[1];
    const float* w1 = (const float*)d_in[2];
    const float* w2 = (const float*)d_in[3];
    float* out = (float*)d_out;

    dim3 block(256);
    dim3 grid(NNETS / NETS_PER_BLOCK);   // 6250, exact
    sparse_mlp_kernel<<<grid, block, 0, stream>>>(x, w0, w1, w2, out);
}